// Round 14
// baseline (298.987 us; speedup 1.0000x reference)
//
#include <hip/hip_runtime.h>

#define NB 2000          // N_BANDS
#define BATCH 8192
#define NT 500           // TARGET
#define NH1 50
#define NH2 10
#define HRc 1999.0f      // 1/h (uniform knots)
#define STEPc (1.0f/1999.0f)
#define MW 56            // padded h width
#define K2 2048          // padded K (16 chunks of 128)
#define XPIT 136         // x LDS pitch in ushorts

// ---- dtype helpers: flag==1 -> bf16 storage, flag==0 -> float32 ----
__device__ __forceinline__ float b2f(unsigned short u) {
    return __uint_as_float(((unsigned int)u) << 16);
}
__device__ __forceinline__ float ulo(unsigned int w) {
    return __uint_as_float(w << 16);
}
__device__ __forceinline__ float uhi(unsigned int w) {
    return __uint_as_float(w & 0xFFFF0000u);
}
__device__ __forceinline__ unsigned short f2b(float f) {
    unsigned int u = __float_as_uint(f);
    return (unsigned short)((u + 0x7FFFu + ((u >> 16) & 1u)) >> 16);
}
__device__ __forceinline__ float ldv(const void* p, int i, int flag) {
    return flag ? b2f(((const unsigned short*)p)[i]) : ((const float*)p)[i];
}
// In-wave dtype detect (proven R12/R13)
__device__ __forceinline__ int wave_detect(const void* x) {
    const unsigned char* xb = (const unsigned char*)x;
    int lane = threadIdx.x & 63;
    int pred = xb[4 * lane + 1] > 0x3F;
    unsigned long long m = __ballot(pred);
    return (__popcll(m) > 4) ? 0 : 1;   // 0 = float32, 1 = bf16
}

// =====================================================================
// P1 (proven R9-R13): exact Thomas recurrences, static register arrays.
// =====================================================================
__global__ __launch_bounds__(64, 1) void p1_stencil(
        const void* __restrict__ xdet, const void* __restrict__ raw_index,
        float* __restrict__ S_coef, int* __restrict__ S_base) {
    __shared__ float cp_tab[64];
    __shared__ float sc[2];
    int tid = threadIdx.x;
    int flag = wave_detect(xdet);
    if (tid == 0) {
        double cp = 0.5;
        cp_tab[0] = 0.5f;
        for (int i = 1; i < 64; ++i) { cp = 1.0 / (4.0 - cp); cp_tab[i] = (float)cp; }
        sc[0] = (float)cp;
        sc[1] = (float)(1.0 / (2.0 - cp));
    }
    __syncthreads();
    int t = blockIdx.x * 64 + tid;
    if (t >= NT) return;
    float c_inf = sc[0], w_last = sc[1];

    float coef_rel[34];
    #pragma unroll
    for (int k = 0; k < 34; ++k) coef_rel[k] = 0.0f;

    float r = ldv(raw_index, t, flag);
    float v = 1.0f / (1.0f + expf(-r));
    int lo = 0, hi = NB;
    while (lo < hi) {
        int mid = (lo + hi) >> 1;
        float tm = (float)mid * STEPc;
        if (tm < v) lo = mid + 1; else hi = mid;
    }
    int idx = lo - 1;
    idx = idx < 0 ? 0 : (idx > NB - 2 ? NB - 2 : idx);
    float f = v - (float)idx * STEPc;
    float u = f * HRc;
    float A = 1.0f + u * u * (2.0f * u - 3.0f);
    float B = u * u * (3.0f - 2.0f * u);
    float C = f * (1.0f - u) * (1.0f - u);
    float D = f * u * (u - 1.0f);

    const float g3 = 3.0f * HRc * HRc;
    const float invhr = 1.0f / HRc;

    #pragma unroll
    for (int row = 0; row < 2; ++row) {
        int j = idx + row;
        float scale = row ? D : C;
        float z[35];
        #pragma unroll
        for (int q = 0; q < 35; ++q) z[q] = 0.0f;
        float w0 = (j <= NB - 2) ? ((j < 64) ? cp_tab[j] : c_inf) : w_last;
        z[17] = w0 * invhr;
        #pragma unroll
        for (int s = 1; s <= 17; ++s) {
            int m = j + s;
            float wm;
            if (m <= NB - 2)      wm = (m < 64) ? cp_tab[m] : c_inf;
            else if (m == NB - 1) wm = w_last;
            else                  wm = 0.0f;
            z[17 + s] = -wm * z[17 + s - 1];
        }
        #pragma unroll
        for (int s = 16; s >= -17; --s) {
            int m = j + s;
            float cpv;
            if (m >= NB - 1 || m < 0) cpv = 0.0f;
            else                      cpv = (m < 64) ? cp_tab[m] : c_inf;
            z[17 + s] = z[17 + s] - cpv * z[17 + s + 1];
        }
        #pragma unroll
        for (int s = -16; s <= 16; ++s) {
            int m = j + s;
            float gv = 0.0f;
            if (m >= 1)      gv += z[17 + s - 1];
            if (m <= NB - 2) gv -= z[17 + s + 1];
            if (m == NB - 1) gv += z[17 + s];
            if (m == 0)      gv -= z[17 + s];
            gv *= g3;
            bool valid = (m >= 0) && (m <= NB - 1);
            coef_rel[s + row + 16] += valid ? scale * gv : 0.0f;
        }
    }
    coef_rel[16] += A;
    coef_rel[17] += B;

    #pragma unroll
    for (int j = 0; j < 34; ++j) S_coef[t * 34 + j] = coef_rel[j];
    S_base[t] = idx;
}

// =====================================================================
// M-BUILD (proven R13): k-pair-packed bf16 Mf2[k2][h].
// =====================================================================
__global__ __launch_bounds__(256) void m_build(
        const void* __restrict__ xdet, const void* __restrict__ W1,
        const float* __restrict__ S_coef, const int* __restrict__ S_base,
        unsigned int* __restrict__ Mf2) {
    __shared__ int sb[NT];
    int tid = threadIdx.x;
    int flag = wave_detect(xdet);
    for (int i = tid; i < NT; i += 256) sb[i] = S_base[i];
    __syncthreads();
    int k2 = blockIdx.x * 4 + (tid >> 6);   // wave-uniform, 0..1023
    int h = tid & 63;
    int hh = h < NH1 ? h : NH1 - 1;
    int k0 = 2 * k2;
    float acc0 = 0.0f, acc1 = 0.0f;
    if (k0 < NB) {
        #pragma unroll 4
        for (int t = 0; t < NT; ++t) {
            int idx = sb[t];
            int rel0 = k0 - idx + 16;
            if (rel0 >= -1 && rel0 < 34) {
                float w1v = ldv(W1, t * NH1 + hh, flag);
                if (rel0 >= 0)  acc0 += S_coef[t * 34 + rel0] * w1v;
                if (rel0 < 33)  acc1 += S_coef[t * 34 + rel0 + 1] * w1v;
            }
        }
    }
    bool ok = (h < NH1) && (k0 < NB);
    unsigned int lo16 = ok ? (unsigned int)f2b(acc0) : 0u;
    unsigned int hi16 = ok ? (unsigned int)f2b(acc1) : 0u;
    if (h < MW) Mf2[(size_t)k2 * MW + h] = lo16 | (hi16 << 16);
}

// =====================================================================
// G-FUSED (R14): register prefetch + LDS double-buffer, ONE barrier per
// chunk. __launch_bounds__(256, 2) so prefetch regs don't spill (R11's
// failure was the missing 2nd arg -> allocator spilled to scratch).
// Tile: 16 rows/block, thread 2r x 4h, 2-way K-split in-block (proven R13).
// =====================================================================
__global__ __launch_bounds__(256, 2) void g_fused(
        const void* __restrict__ x, const unsigned int* __restrict__ Mf2,
        const void* __restrict__ b1, const void* __restrict__ W2,
        const void* __restrict__ b2, const void* __restrict__ W3,
        const void* __restrict__ b3, void* __restrict__ out) {
    __shared__ __align__(16) unsigned short lx[2][16 * XPIT];  // 8.7 KB
    __shared__ __align__(16) unsigned int lm2[2][64 * MW];     // 28.7 KB
    __shared__ float ct0[16][57];
    __shared__ float ct1[16][57];
    __shared__ float Wmlp[NH1 * NH2 + NH1 + NH2 + NH2 + 1];

    int tid = threadIdx.x;
    int b0 = blockIdx.x * 16;
    int flag = wave_detect(x);

    for (int i = tid; i < NH1 * NH2; i += 256) Wmlp[i] = ldv(W2, i, flag);
    if (tid < NH1) Wmlp[500 + tid] = ldv(b1, tid, flag);
    if (tid < NH2) Wmlp[550 + tid] = ldv(b2, tid, flag);
    if (tid < NH2) Wmlp[560 + tid] = ldv(W3, tid, flag);
    if (tid == 0)  Wmlp[570] = ldv(b3, 0, flag);

    int rg = tid & 7;            // rows 2rg, 2rg+1
    int hg = (tid >> 3) & 15;    // h quad
    int hgc = hg > 13 ? 13 : hg;
    int ks = tid >> 7;           // K-split half

    int xrow = tid >> 4, xseg = tid & 15;
    const unsigned short* xs = (const unsigned short*)x;
    const float* xf = (const float*)x;

    // prefetch registers
    uint4  px;                    // bf16 path x
    float4 pxf0, pxf1;            // f32 path x
    uint4  pm[4];                 // M (4th valid for tid<128)

    // ---- prefetch chunk 0 ----
    {
        int base = 0;
        int gk = base + xseg * 8;
        if (flag) {
            px = (gk < NB) ? *(const uint4*)(xs + (size_t)(b0 + xrow) * NB + gk)
                           : make_uint4(0u, 0u, 0u, 0u);
        } else {
            pxf0 = make_float4(0.f, 0.f, 0.f, 0.f);
            pxf1 = pxf0;
            if (gk < NB) {
                pxf0 = *(const float4*)(xf + (size_t)(b0 + xrow) * NB + gk);
                pxf1 = *(const float4*)(xf + (size_t)(b0 + xrow) * NB + gk + 4);
            }
        }
        #pragma unroll
        for (int it = 0; it < 4; ++it) {
            int id = tid + it * 256;
            if (id < 896) {
                int k2l = id / 14, hq = id - k2l * 14;
                pm[it] = *(const uint4*)(Mf2 + (size_t)k2l * MW + hq * 4);
            }
        }
    }
    // ---- store chunk 0 into buffer 0 ----
    {
        uint4 val;
        if (flag) val = px;
        else {
            val.x = (unsigned int)f2b(pxf0.x) | ((unsigned int)f2b(pxf0.y) << 16);
            val.y = (unsigned int)f2b(pxf0.z) | ((unsigned int)f2b(pxf0.w) << 16);
            val.z = (unsigned int)f2b(pxf1.x) | ((unsigned int)f2b(pxf1.y) << 16);
            val.w = (unsigned int)f2b(pxf1.z) | ((unsigned int)f2b(pxf1.w) << 16);
        }
        *(uint4*)&lx[0][xrow * XPIT + xseg * 8] = val;
        #pragma unroll
        for (int it = 0; it < 4; ++it) {
            int id = tid + it * 256;
            if (id < 896) {
                int k2l = id / 14, hq = id - k2l * 14;
                *(uint4*)&lm2[0][k2l * MW + hq * 4] = pm[it];
            }
        }
    }

    float acc[2][4];
    #pragma unroll
    for (int i = 0; i < 2; ++i)
        #pragma unroll
        for (int j = 0; j < 4; ++j) acc[i][j] = 0.0f;

    for (int c = 0; c < 16; ++c) {
        int buf = c & 1;
        __syncthreads();   // stores of chunk c visible; compute c-1 done

        // ---- issue prefetch of chunk c+1 (lands during compute) ----
        if (c + 1 < 16) {
            int base = (c + 1) * 128;
            int base2 = (c + 1) * 64;
            int gk = base + xseg * 8;
            if (flag) {
                px = (gk < NB) ? *(const uint4*)(xs + (size_t)(b0 + xrow) * NB + gk)
                               : make_uint4(0u, 0u, 0u, 0u);
            } else {
                pxf0 = make_float4(0.f, 0.f, 0.f, 0.f);
                pxf1 = pxf0;
                if (gk < NB) {
                    pxf0 = *(const float4*)(xf + (size_t)(b0 + xrow) * NB + gk);
                    pxf1 = *(const float4*)(xf + (size_t)(b0 + xrow) * NB + gk + 4);
                }
            }
            #pragma unroll
            for (int it = 0; it < 4; ++it) {
                int id = tid + it * 256;
                if (id < 896) {
                    int k2l = id / 14, hq = id - k2l * 14;
                    pm[it] = *(const uint4*)(Mf2 + (size_t)(base2 + k2l) * MW + hq * 4);
                }
            }
        }

        // ---- compute chunk c from buf ----
        int xb0 = (2 * rg) * XPIT;
        int xb1 = xb0 + XPIT;
        #pragma unroll
        for (int kbi = 0; kbi < 8; ++kbi) {
            int kb = ks * 8 + kbi;
            uint4 a = *(const uint4*)&lx[buf][xb0 + kb * 8];
            uint4 b = *(const uint4*)&lx[buf][xb1 + kb * 8];
            float xa[8], xc[8];
            xa[0] = ulo(a.x); xa[1] = uhi(a.x); xa[2] = ulo(a.y); xa[3] = uhi(a.y);
            xa[4] = ulo(a.z); xa[5] = uhi(a.z); xa[6] = ulo(a.w); xa[7] = uhi(a.w);
            xc[0] = ulo(b.x); xc[1] = uhi(b.x); xc[2] = ulo(b.y); xc[3] = uhi(b.y);
            xc[4] = ulo(b.z); xc[5] = uhi(b.z); xc[6] = ulo(b.w); xc[7] = uhi(b.w);
            #pragma unroll
            for (int q = 0; q < 4; ++q) {
                uint4 mv = *(const uint4*)&lm2[buf][(kb * 4 + q) * MW + hgc * 4];
                float me[4], mo[4];
                me[0] = ulo(mv.x); mo[0] = uhi(mv.x);
                me[1] = ulo(mv.y); mo[1] = uhi(mv.y);
                me[2] = ulo(mv.z); mo[2] = uhi(mv.z);
                me[3] = ulo(mv.w); mo[3] = uhi(mv.w);
                float xe0 = xa[2 * q], xo0 = xa[2 * q + 1];
                float xe1 = xc[2 * q], xo1 = xc[2 * q + 1];
                #pragma unroll
                for (int j = 0; j < 4; ++j) {
                    acc[0][j] = fmaf(xe0, me[j], acc[0][j]);
                    acc[0][j] = fmaf(xo0, mo[j], acc[0][j]);
                    acc[1][j] = fmaf(xe1, me[j], acc[1][j]);
                    acc[1][j] = fmaf(xo1, mo[j], acc[1][j]);
                }
            }
        }

        // ---- store prefetched chunk c+1 into the other buffer ----
        if (c + 1 < 16) {
            int nbuf = buf ^ 1;
            uint4 val;
            if (flag) val = px;
            else {
                val.x = (unsigned int)f2b(pxf0.x) | ((unsigned int)f2b(pxf0.y) << 16);
                val.y = (unsigned int)f2b(pxf0.z) | ((unsigned int)f2b(pxf0.w) << 16);
                val.z = (unsigned int)f2b(pxf1.x) | ((unsigned int)f2b(pxf1.y) << 16);
                val.w = (unsigned int)f2b(pxf1.z) | ((unsigned int)f2b(pxf1.w) << 16);
            }
            *(uint4*)&lx[nbuf][xrow * XPIT + xseg * 8] = val;
            #pragma unroll
            for (int it = 0; it < 4; ++it) {
                int id = tid + it * 256;
                if (id < 896) {
                    int k2l = id / 14, hq = id - k2l * 14;
                    *(uint4*)&lm2[nbuf][k2l * MW + hq * 4] = pm[it];
                }
            }
        }
    }

    __syncthreads();
    if (hg < 14) {
        #pragma unroll
        for (int i = 0; i < 2; ++i)
            #pragma unroll
            for (int j = 0; j < 4; ++j) {
                if (ks == 0) ct0[2 * rg + i][4 * hg + j] = acc[i][j];
                else         ct1[2 * rg + i][4 * hg + j] = acc[i][j];
            }
    }
    __syncthreads();

    if (tid < 16) {
        float h1v[NH1];
        #pragma unroll
        for (int h = 0; h < NH1; ++h) {
            float vv = ct0[tid][h] + ct1[tid][h] + Wmlp[500 + h];
            h1v[h] = vv >= 0.0f ? vv : 0.01f * vv;
        }
        float o = Wmlp[570];
        for (int j = 0; j < NH2; ++j) {
            float a = Wmlp[550 + j];
            #pragma unroll
            for (int h = 0; h < NH1; ++h)
                a = fmaf(h1v[h], Wmlp[h * NH2 + j], a);
            a = a >= 0.0f ? a : 0.01f * a;
            o = fmaf(a, Wmlp[560 + j], o);
        }
        int b = b0 + tid;
        if (flag) ((unsigned short*)out)[b] = f2b(o);
        else      ((float*)out)[b] = o;
    }
}

extern "C" void kernel_launch(void* const* d_in, const int* in_sizes, int n_in,
                              void* d_out, int out_size, void* d_ws, size_t ws_size,
                              hipStream_t stream) {
    const void* x   = d_in[0];
    const void* raw = d_in[1];
    const void* W1  = d_in[2];
    const void* b1  = d_in[3];
    const void* W2  = d_in[4];
    const void* b2  = d_in[5];
    const void* W3  = d_in[6];
    const void* b3  = d_in[7];

    // Workspace: S_base 512 i32 | S_coef 17000 f32 | Mf2 1024*56 u32 ≈ 300 KB.
    // No atomics, no pre-zeroing; every read location written each launch.
    float* w      = (float*)d_ws;
    int*   S_base = (int*)w;
    float* S_coef = w + 512;
    unsigned int* Mf2 = (unsigned int*)(w + 17512);

    p1_stencil<<<8, 64, 0, stream>>>(x, raw, S_coef, S_base);
    m_build<<<256, 256, 0, stream>>>(x, W1, S_coef, S_base, Mf2);
    g_fused<<<512, 256, 0, stream>>>(x, Mf2, b1, W2, b2, W3, b3, d_out);
}

// Round 15
// 197.933 us; speedup vs baseline: 1.5105x; 1.5105x over previous
//
#include <hip/hip_runtime.h>

#define NB 2000          // N_BANDS
#define BATCH 8192
#define NT 500           // TARGET
#define NH1 50
#define NH2 10
#define HRc 1999.0f      // 1/h (uniform knots)
#define STEPc (1.0f/1999.0f)
#define MW 56            // M width (u32 per k-pair), UNPADDED for DMA
#define K2 2048          // padded K (16 chunks of 128)
#define XP 128           // x LDS pitch in ushorts, UNPADDED for DMA

// ---- dtype helpers ----
__device__ __forceinline__ float b2f(unsigned short u) {
    return __uint_as_float(((unsigned int)u) << 16);
}
__device__ __forceinline__ float ulo(unsigned int w) {
    return __uint_as_float(w << 16);
}
__device__ __forceinline__ float uhi(unsigned int w) {
    return __uint_as_float(w & 0xFFFF0000u);
}
__device__ __forceinline__ unsigned short f2b(float f) {
    unsigned int u = __float_as_uint(f);
    return (unsigned short)((u + 0x7FFFu + ((u >> 16) & 1u)) >> 16);
}
__device__ __forceinline__ float ldv(const void* p, int i, int flag) {
    return flag ? b2f(((const unsigned short*)p)[i]) : ((const float*)p)[i];
}
// In-wave dtype detect (proven R12-R14)
__device__ __forceinline__ int wave_detect(const void* x) {
    const unsigned char* xb = (const unsigned char*)x;
    int lane = threadIdx.x & 63;
    int pred = xb[4 * lane + 1] > 0x3F;
    unsigned long long m = __ballot(pred);
    return (__popcll(m) > 4) ? 0 : 1;   // 0 = float32, 1 = bf16
}
// Async global->LDS DMA, 16B/lane; dest = wave-uniform base + lane*16.
__device__ __forceinline__ void async16(const void* g, void* l) {
    __builtin_amdgcn_global_load_lds(
        (const __attribute__((address_space(1))) void*)g,
        (__attribute__((address_space(3))) void*)l, 16, 0, 0);
}

// =====================================================================
// P1 (proven R9-R14): exact Thomas recurrences, static register arrays.
// =====================================================================
__global__ __launch_bounds__(64, 1) void p1_stencil(
        const void* __restrict__ xdet, const void* __restrict__ raw_index,
        float* __restrict__ S_coef, int* __restrict__ S_base) {
    __shared__ float cp_tab[64];
    __shared__ float sc[2];
    int tid = threadIdx.x;
    int flag = wave_detect(xdet);
    if (tid == 0) {
        double cp = 0.5;
        cp_tab[0] = 0.5f;
        for (int i = 1; i < 64; ++i) { cp = 1.0 / (4.0 - cp); cp_tab[i] = (float)cp; }
        sc[0] = (float)cp;
        sc[1] = (float)(1.0 / (2.0 - cp));
    }
    __syncthreads();
    int t = blockIdx.x * 64 + tid;
    if (t >= NT) return;
    float c_inf = sc[0], w_last = sc[1];

    float coef_rel[34];
    #pragma unroll
    for (int k = 0; k < 34; ++k) coef_rel[k] = 0.0f;

    float r = ldv(raw_index, t, flag);
    float v = 1.0f / (1.0f + expf(-r));
    int lo = 0, hi = NB;
    while (lo < hi) {
        int mid = (lo + hi) >> 1;
        float tm = (float)mid * STEPc;
        if (tm < v) lo = mid + 1; else hi = mid;
    }
    int idx = lo - 1;
    idx = idx < 0 ? 0 : (idx > NB - 2 ? NB - 2 : idx);
    float f = v - (float)idx * STEPc;
    float u = f * HRc;
    float A = 1.0f + u * u * (2.0f * u - 3.0f);
    float B = u * u * (3.0f - 2.0f * u);
    float C = f * (1.0f - u) * (1.0f - u);
    float D = f * u * (u - 1.0f);

    const float g3 = 3.0f * HRc * HRc;
    const float invhr = 1.0f / HRc;

    #pragma unroll
    for (int row = 0; row < 2; ++row) {
        int j = idx + row;
        float scale = row ? D : C;
        float z[35];
        #pragma unroll
        for (int q = 0; q < 35; ++q) z[q] = 0.0f;
        float w0 = (j <= NB - 2) ? ((j < 64) ? cp_tab[j] : c_inf) : w_last;
        z[17] = w0 * invhr;
        #pragma unroll
        for (int s = 1; s <= 17; ++s) {
            int m = j + s;
            float wm;
            if (m <= NB - 2)      wm = (m < 64) ? cp_tab[m] : c_inf;
            else if (m == NB - 1) wm = w_last;
            else                  wm = 0.0f;
            z[17 + s] = -wm * z[17 + s - 1];
        }
        #pragma unroll
        for (int s = 16; s >= -17; --s) {
            int m = j + s;
            float cpv;
            if (m >= NB - 1 || m < 0) cpv = 0.0f;
            else                      cpv = (m < 64) ? cp_tab[m] : c_inf;
            z[17 + s] = z[17 + s] - cpv * z[17 + s + 1];
        }
        #pragma unroll
        for (int s = -16; s <= 16; ++s) {
            int m = j + s;
            float gv = 0.0f;
            if (m >= 1)      gv += z[17 + s - 1];
            if (m <= NB - 2) gv -= z[17 + s + 1];
            if (m == NB - 1) gv += z[17 + s];
            if (m == 0)      gv -= z[17 + s];
            gv *= g3;
            bool valid = (m >= 0) && (m <= NB - 1);
            coef_rel[s + row + 16] += valid ? scale * gv : 0.0f;
        }
    }
    coef_rel[16] += A;
    coef_rel[17] += B;

    #pragma unroll
    for (int j = 0; j < 34; ++j) S_coef[t * 34 + j] = coef_rel[j];
    S_base[t] = idx;
}

// =====================================================================
// M-BUILD (proven R13/R14): k-pair-packed bf16 Mf2[k2][h], zero-padded.
// =====================================================================
__global__ __launch_bounds__(256) void m_build(
        const void* __restrict__ xdet, const void* __restrict__ W1,
        const float* __restrict__ S_coef, const int* __restrict__ S_base,
        unsigned int* __restrict__ Mf2) {
    __shared__ int sb[NT];
    int tid = threadIdx.x;
    int flag = wave_detect(xdet);
    for (int i = tid; i < NT; i += 256) sb[i] = S_base[i];
    __syncthreads();
    int k2 = blockIdx.x * 4 + (tid >> 6);
    int h = tid & 63;
    int hh = h < NH1 ? h : NH1 - 1;
    int k0 = 2 * k2;
    float acc0 = 0.0f, acc1 = 0.0f;
    if (k0 < NB) {
        #pragma unroll 4
        for (int t = 0; t < NT; ++t) {
            int idx = sb[t];
            int rel0 = k0 - idx + 16;
            if (rel0 >= -1 && rel0 < 34) {
                float w1v = ldv(W1, t * NH1 + hh, flag);
                if (rel0 >= 0)  acc0 += S_coef[t * 34 + rel0] * w1v;
                if (rel0 < 33)  acc1 += S_coef[t * 34 + rel0 + 1] * w1v;
            }
        }
    }
    bool ok = (h < NH1) && (k0 < NB);
    unsigned int lo16 = ok ? (unsigned int)f2b(acc0) : 0u;
    unsigned int hi16 = ok ? (unsigned int)f2b(acc1) : 0u;
    if (h < MW) Mf2[(size_t)k2 * MW + h] = lo16 | (hi16 << 16);
}

// =====================================================================
// G-FUSED (R15): async global_load_lds staging (zero prefetch VGPRs),
// LDS double-buffer, ONE barrier per chunk. DMA dest = wave-uniform
// base + lane*16 => unpadded layouts; x uses XOR source swizzle
// (slot s of row r holds source chunk s^(r&7)) to keep reads <=2-way.
// Tile (proven R13): 16 rows/block, thread 2r x 4h, 2-way in-block K-split.
// =====================================================================
__global__ __launch_bounds__(256) void g_fused(
        const void* __restrict__ x, const unsigned int* __restrict__ Mf2,
        const void* __restrict__ b1, const void* __restrict__ W2,
        const void* __restrict__ b2, const void* __restrict__ W3,
        const void* __restrict__ b3, void* __restrict__ out) {
    __shared__ __align__(16) unsigned short lx[2][16 * XP];   // 2 x 4 KB
    __shared__ __align__(16) unsigned int lm2[2][64 * MW];    // 2 x 14.3 KB
    __shared__ float ct0[16][57];
    __shared__ float ct1[16][57];
    __shared__ float Wmlp[NH1 * NH2 + NH1 + NH2 + NH2 + 1];

    int tid = threadIdx.x;
    int b0 = blockIdx.x * 16;
    int flag = wave_detect(x);

    for (int i = tid; i < NH1 * NH2; i += 256) Wmlp[i] = ldv(W2, i, flag);
    if (tid < NH1) Wmlp[500 + tid] = ldv(b1, tid, flag);
    if (tid < NH2) Wmlp[550 + tid] = ldv(b2, tid, flag);
    if (tid < NH2) Wmlp[560 + tid] = ldv(W3, tid, flag);
    if (tid == 0)  Wmlp[570] = ldv(b3, 0, flag);

    int rg = tid & 7;            // rows 2rg, 2rg+1
    int hg = (tid >> 3) & 15;    // h quad
    int hgc = hg > 13 ? 13 : hg;
    int ks = tid >> 7;           // K-split half
    int wv = tid >> 6;           // wave id (uniform)

    int xrow = tid >> 4, xseg = tid & 15;
    int sseg = xseg ^ (xrow & 7);           // XOR source swizzle
    const unsigned short* xs = (const unsigned short*)x;
    const float* xf = (const float*)x;

    float acc[2][4];
    #pragma unroll
    for (int i = 0; i < 2; ++i)
        #pragma unroll
        for (int j = 0; j < 4; ++j) acc[i][j] = 0.0f;

    // ---- prologue: stage chunk 0 into buffer 0 ----
    {
        int gk = sseg * 8;                          // chunk 0: always < NB
        if (flag) {
            async16(xs + (size_t)(b0 + xrow) * NB + gk, &lx[0][wv * 256]);
            #pragma unroll
            for (int it = 0; it < 4; ++it) {
                int id = tid + it * 256;
                if (id < 896)
                    async16(Mf2 + (size_t)id * 4,
                            &lm2[0][it * 1024 + wv * 256]);
            }
        } else {
            float4 v0 = *(const float4*)(xf + (size_t)(b0 + xrow) * NB + gk);
            float4 v1 = *(const float4*)(xf + (size_t)(b0 + xrow) * NB + gk + 4);
            uint4 val;
            val.x = (unsigned int)f2b(v0.x) | ((unsigned int)f2b(v0.y) << 16);
            val.y = (unsigned int)f2b(v0.z) | ((unsigned int)f2b(v0.w) << 16);
            val.z = (unsigned int)f2b(v1.x) | ((unsigned int)f2b(v1.y) << 16);
            val.w = (unsigned int)f2b(v1.z) | ((unsigned int)f2b(v1.w) << 16);
            *(uint4*)&lx[0][xrow * XP + xseg * 8] = val;
            #pragma unroll
            for (int it = 0; it < 4; ++it) {
                int id = tid + it * 256;
                if (id < 896)
                    *(uint4*)&lm2[0][id * 4] = *(const uint4*)(Mf2 + (size_t)id * 4);
            }
        }
    }

    for (int c = 0; c < 16; ++c) {
        int buf = c & 1;
        __syncthreads();   // drains chunk-c DMA; compute of c-1 finished

        // ---- issue chunk c+1 into the other buffer (overlaps compute) ----
        if (c + 1 < 16) {
            int kbase = (c + 1) * 128;
            int base2 = (c + 1) * 64;
            int nbuf = buf ^ 1;
            int gk = kbase + sseg * 8;
            if (gk > NB - 8) gk = NB - 8;           // clamp: dup data x M-pad(0)
            if (flag) {
                async16(xs + (size_t)(b0 + xrow) * NB + gk, &lx[nbuf][wv * 256]);
                #pragma unroll
                for (int it = 0; it < 4; ++it) {
                    int id = tid + it * 256;
                    if (id < 896)
                        async16(Mf2 + (size_t)base2 * MW + (size_t)id * 4,
                                &lm2[nbuf][it * 1024 + wv * 256]);
                }
            } else {
                float4 v0 = *(const float4*)(xf + (size_t)(b0 + xrow) * NB + gk);
                float4 v1 = *(const float4*)(xf + (size_t)(b0 + xrow) * NB + gk + 4);
                uint4 val;
                val.x = (unsigned int)f2b(v0.x) | ((unsigned int)f2b(v0.y) << 16);
                val.y = (unsigned int)f2b(v0.z) | ((unsigned int)f2b(v0.w) << 16);
                val.z = (unsigned int)f2b(v1.x) | ((unsigned int)f2b(v1.y) << 16);
                val.w = (unsigned int)f2b(v1.z) | ((unsigned int)f2b(v1.w) << 16);
                *(uint4*)&lx[nbuf][xrow * XP + xseg * 8] = val;
                #pragma unroll
                for (int it = 0; it < 4; ++it) {
                    int id = tid + it * 256;
                    if (id < 896)
                        *(uint4*)&lm2[nbuf][id * 4] =
                            *(const uint4*)(Mf2 + (size_t)base2 * MW + (size_t)id * 4);
                }
            }
        }

        // ---- compute chunk c from buf ----
        int xb0 = (2 * rg) * XP;
        int xb1 = xb0 + XP;
        int e0 = (2 * rg) & 7, e1 = (2 * rg + 1) & 7;   // swizzle keys
        #pragma unroll
        for (int kbi = 0; kbi < 8; ++kbi) {
            int kb = ks * 8 + kbi;
            uint4 a = *(const uint4*)&lx[buf][xb0 + (kb ^ e0) * 8];
            uint4 b = *(const uint4*)&lx[buf][xb1 + (kb ^ e1) * 8];
            float xa[8], xc[8];
            xa[0] = ulo(a.x); xa[1] = uhi(a.x); xa[2] = ulo(a.y); xa[3] = uhi(a.y);
            xa[4] = ulo(a.z); xa[5] = uhi(a.z); xa[6] = ulo(a.w); xa[7] = uhi(a.w);
            xc[0] = ulo(b.x); xc[1] = uhi(b.x); xc[2] = ulo(b.y); xc[3] = uhi(b.y);
            xc[4] = ulo(b.z); xc[5] = uhi(b.z); xc[6] = ulo(b.w); xc[7] = uhi(b.w);
            #pragma unroll
            for (int q = 0; q < 4; ++q) {
                uint4 mv = *(const uint4*)&lm2[buf][(kb * 4 + q) * MW + hgc * 4];
                float me[4], mo[4];
                me[0] = ulo(mv.x); mo[0] = uhi(mv.x);
                me[1] = ulo(mv.y); mo[1] = uhi(mv.y);
                me[2] = ulo(mv.z); mo[2] = uhi(mv.z);
                me[3] = ulo(mv.w); mo[3] = uhi(mv.w);
                float xe0 = xa[2 * q], xo0 = xa[2 * q + 1];
                float xe1 = xc[2 * q], xo1 = xc[2 * q + 1];
                #pragma unroll
                for (int j = 0; j < 4; ++j) {
                    acc[0][j] = fmaf(xe0, me[j], acc[0][j]);
                    acc[0][j] = fmaf(xo0, mo[j], acc[0][j]);
                    acc[1][j] = fmaf(xe1, me[j], acc[1][j]);
                    acc[1][j] = fmaf(xo1, mo[j], acc[1][j]);
                }
            }
        }
    }

    __syncthreads();
    if (hg < 14) {
        #pragma unroll
        for (int i = 0; i < 2; ++i)
            #pragma unroll
            for (int j = 0; j < 4; ++j) {
                if (ks == 0) ct0[2 * rg + i][4 * hg + j] = acc[i][j];
                else         ct1[2 * rg + i][4 * hg + j] = acc[i][j];
            }
    }
    __syncthreads();

    if (tid < 16) {
        float h1v[NH1];
        #pragma unroll
        for (int h = 0; h < NH1; ++h) {
            float vv = ct0[tid][h] + ct1[tid][h] + Wmlp[500 + h];
            h1v[h] = vv >= 0.0f ? vv : 0.01f * vv;
        }
        float o = Wmlp[570];
        for (int j = 0; j < NH2; ++j) {
            float a = Wmlp[550 + j];
            #pragma unroll
            for (int h = 0; h < NH1; ++h)
                a = fmaf(h1v[h], Wmlp[h * NH2 + j], a);
            a = a >= 0.0f ? a : 0.01f * a;
            o = fmaf(a, Wmlp[560 + j], o);
        }
        int b = b0 + tid;
        if (flag) ((unsigned short*)out)[b] = f2b(o);
        else      ((float*)out)[b] = o;
    }
}

extern "C" void kernel_launch(void* const* d_in, const int* in_sizes, int n_in,
                              void* d_out, int out_size, void* d_ws, size_t ws_size,
                              hipStream_t stream) {
    const void* x   = d_in[0];
    const void* raw = d_in[1];
    const void* W1  = d_in[2];
    const void* b1  = d_in[3];
    const void* W2  = d_in[4];
    const void* b2  = d_in[5];
    const void* W3  = d_in[6];
    const void* b3  = d_in[7];

    // Workspace: S_base 512 i32 | S_coef 17000 f32 | Mf2 1024*56 u32 ≈ 300 KB.
    // No atomics, no pre-zeroing; every read location written each launch.
    float* w      = (float*)d_ws;
    int*   S_base = (int*)w;
    float* S_coef = w + 512;
    unsigned int* Mf2 = (unsigned int*)(w + 17512);

    p1_stencil<<<8, 64, 0, stream>>>(x, raw, S_coef, S_base);
    m_build<<<256, 256, 0, stream>>>(x, W1, S_coef, S_base, Mf2);
    g_fused<<<512, 256, 0, stream>>>(x, Mf2, b1, W2, b2, W3, b3, d_out);
}